// Round 5
// baseline (3287.794 us; speedup 1.0000x reference)
//
#include <hip/hip_runtime.h>

#define B_SZ   256
#define T_SZ   1000
#define N_IN   128
#define UNITS  512
#define WIN    128       // fixed straight-line window (slots 0..127)

// ---------------------------------------------------------------------------
// Phase 0: Wz[513][512] in d_ws: W_rec with diagonal zeroed, plus an all-zero
// row 512. Gathers of pad slots (idx=512) and diagonal then return exact
// +0.0f, making the accumulation chain unconditional while bit-identical to
// the predicated r1 chain. Rebuilt every call (d_ws is not persistent).
// Needs 513*512*4 = 1050624 bytes of workspace.
// ---------------------------------------------------------------------------
__global__ __launch_bounds__(512) void wz_prep(const float* __restrict__ Wr,
                                               float* __restrict__ Wz) {
    const int c = threadIdx.x, r = blockIdx.x;
    Wz[(size_t)r * UNITS + c] =
        (r >= UNITS || r == c) ? 0.0f : Wr[(size_t)r * UNITS + c];
}

// ---------------------------------------------------------------------------
// Phase 1: C[M,512] = X[M,128] @ W[128,512],  M = B*T = 256000, fp32.
// (unchanged — measured at ~fp32 vector roofline, ~210 us)
// ---------------------------------------------------------------------------
__global__ __launch_bounds__(256) void gemm_in(const float* __restrict__ X,
                                               const float* __restrict__ W,
                                               float* __restrict__ C) {
    __shared__ __align__(16) float As[32][128];  // As[k][m] (transposed x tile)
    __shared__ __align__(16) float Bs[32][128];  // Bs[k][n]

    const int tid = threadIdx.x;
    const int ntile = blockIdx.x & 3;        // 512/128 = 4 n-tiles
    const int mtile = blockIdx.x >> 2;       // 2000 m-tiles
    const int m0 = mtile * 128, n0 = ntile * 128;
    const int tm  = (tid >> 4) * 8;          // 16 m-groups of 8
    const int tn4 = (tid & 15) * 4;          // 16 n-groups of 4 (+ mirror at +64)

    float acc[8][8];
#pragma unroll
    for (int i = 0; i < 8; ++i)
#pragma unroll
        for (int j = 0; j < 8; ++j) acc[i][j] = 0.0f;

    for (int k0 = 0; k0 < 128; k0 += 32) {
        __syncthreads();
#pragma unroll
        for (int r = 0; r < 4; ++r) {
            int li  = r * 256 + tid;          // 0..1023 float4 slots
            int row = li >> 3;                // 0..127
            int ch  = li & 7;                 // 0..7 (4 floats each)
            float4 a = *(const float4*)&X[(size_t)(m0 + row) * 128 + k0 + ch * 4];
            As[ch * 4 + 0][row] = a.x;
            As[ch * 4 + 1][row] = a.y;
            As[ch * 4 + 2][row] = a.z;
            As[ch * 4 + 3][row] = a.w;
        }
#pragma unroll
        for (int r = 0; r < 4; ++r) {
            int li = r * 256 + tid;
            int kk = li >> 5;                 // 0..31
            int n4 = li & 31;                 // 0..31
            *(float4*)&Bs[kk][n4 * 4] =
                *(const float4*)&W[(size_t)(k0 + kk) * 512 + n0 + n4 * 4];
        }
        __syncthreads();

#pragma unroll 8
        for (int k = 0; k < 32; ++k) {
            float4 a0 = *(const float4*)&As[k][tm];
            float4 a1 = *(const float4*)&As[k][tm + 4];
            float4 b0 = *(const float4*)&Bs[k][tn4];
            float4 b1 = *(const float4*)&Bs[k][tn4 + 64];
            const float av[8] = {a0.x, a0.y, a0.z, a0.w, a1.x, a1.y, a1.z, a1.w};
            const float bv[8] = {b0.x, b0.y, b0.z, b0.w, b1.x, b1.y, b1.z, b1.w};
#pragma unroll
            for (int i = 0; i < 8; ++i)
#pragma unroll
                for (int j = 0; j < 8; ++j)
                    acc[i][j] = fmaf(av[i], bv[j], acc[i][j]);
        }
    }

#pragma unroll
    for (int i = 0; i < 8; ++i) {
        size_t row = (size_t)(m0 + tm + i) * 512;
        float4 c0 = make_float4(acc[i][0], acc[i][1], acc[i][2], acc[i][3]);
        float4 c1 = make_float4(acc[i][4], acc[i][5], acc[i][6], acc[i][7]);
        *(float4*)&C[row + n0 + tn4]      = c0;
        *(float4*)&C[row + n0 + 64 + tn4] = c1;
    }
}

// ---------------------------------------------------------------------------
// Phase 2: ALIF scan. One WG per batch (256 WGs x 512 threads), thread u
// owns unit u. Latency-bound => fixed 128-slot straight-line window:
//   - 32x ds_read_b128 index burst + 128 gather issues, ALL pinned above the
//     add chain by sched_barrier(0) (r3's failure was the scheduler sinking
//     loads into the chain; this forbids it).
//   - adds are UNCONDITIONAL __fadd_rn in ascending slot order: pad slots
//     (idx=512) and the diagonal gather exact +0.0f from Wz — bit-identical
//     to the predicated r1 chain (absmax 0.0).
//   - cnt>128 (early transient) falls into r1's proven 8-in-flight loop.
// List rebuild: r1's contiguous cross-wave-prefix scheme (proven), with 128
// pad entries of 512 after total.
// ---------------------------------------------------------------------------
__global__ __launch_bounds__(512, 2) void alif_scan(const float* __restrict__ Wz,
                                                    float* __restrict__ IO) {
    const int b = blockIdx.x;
    const int u = threadIdx.x;
    const int w = u >> 6;                    // wave id (0..7)
    const int lane = u & 63;

    __shared__ __align__(16) int s_list[UNITS + WIN];  // 512 + 128 pad
    __shared__ int s_cnt[8];
    __shared__ int s_total;

    const float DECAY   = 0.95122942450071400910f;   // exp(-1/20)
    const float OMD     = 1.0f - DECAY;
    const float DECAY_B = 0.99501247919268232342f;   // exp(-1/200)
    const float OMDB    = 1.0f - DECAY_B;

    float v = 0.0f, ad = 0.0f, z = 0.0f;

    const float* wz = Wz + u;                         // column u of Wz
    float* io = IO + (size_t)b * (T_SZ * UNITS) + u;  // [t][u] slab for batch b

    // init: whole list = pad idx 512, total = 0
    s_list[u] = UNITS;
    if (u < WIN) s_list[UNITS + u] = UNITS;
    if (u == 0) s_total = 0;
    __syncthreads();

    float i_cur = io[0];

    for (int t = 0; t < T_SZ; ++t) {
        // prefetch next step's input current
        float i_next = io[(t + 1 < T_SZ ? t + 1 : t) * UNITS];

        const int cnt = s_total;
        float acc = 0.0f;

        // ---- fixed 128-slot window: all loads issued, then pinned adds ----
        {
            float G[WIN];
#pragma unroll
            for (int blk = 0; blk < 4; ++blk) {
                int4 I[8];
#pragma unroll
                for (int r = 0; r < 8; ++r)
                    I[r] = *(const int4*)(s_list + blk * 32 + 4 * r);
#pragma unroll
                for (int r = 0; r < 8; ++r) {
                    G[blk * 32 + 4 * r + 0] = wz[I[r].x * UNITS];
                    G[blk * 32 + 4 * r + 1] = wz[I[r].y * UNITS];
                    G[blk * 32 + 4 * r + 2] = wz[I[r].z * UNITS];
                    G[blk * 32 + 4 * r + 3] = wz[I[r].w * UNITS];
                }
            }
            __builtin_amdgcn_sched_barrier(0);  // loads stay above the chain
#pragma unroll
            for (int i = 0; i < WIN; ++i) acc = __fadd_rn(acc, G[i]);
        }

        // ---- residual (cnt > 128, early transient only): r1 pattern ----
        for (int k = WIN; k < cnt; k += 8) {
            int4 Ja = *(const int4*)(s_list + k);
            int4 Jb = *(const int4*)(s_list + k + 4);
            float g0 = wz[Ja.x * UNITS];
            float g1 = wz[Ja.y * UNITS];
            float g2 = wz[Ja.z * UNITS];
            float g3 = wz[Ja.w * UNITS];
            float g4 = wz[Jb.x * UNITS];
            float g5 = wz[Jb.y * UNITS];
            float g6 = wz[Jb.z * UNITS];
            float g7 = wz[Jb.w * UNITS];
            acc = __fadd_rn(acc, g0);
            acc = __fadd_rn(acc, g1);
            acc = __fadd_rn(acc, g2);
            acc = __fadd_rn(acc, g3);
            acc = __fadd_rn(acc, g4);
            acc = __fadd_rn(acc, g5);
            acc = __fadd_rn(acc, g6);
            acc = __fadd_rn(acc, g7);
        }

        // ---- elementwise state update — exact reference op order ----
        float newb = __fadd_rn(__fmul_rn(DECAY_B, ad), __fmul_rn(OMDB, z));
        float thr  = __fadd_rn(0.01f, __fmul_rn(newb, 1.6f));
        float it   = __fadd_rn(__fadd_rn(i_cur, acc), 0.0f);       // + ADD_CUR
        float ires = __fmul_rn(__fmul_rn(z, thr), 1.0f);           // * DT
        float newv = __fsub_rn(
            __fadd_rn(__fmul_rn(DECAY, v), __fmul_rn(OMD, it)), ires);
        float zn = (newv > thr) ? 1.0f : 0.0f;      // refractory is a no-op

        io[t * UNITS] = zn;                          // overwrite i_in with z
        v = newv; ad = newb; z = zn; i_cur = i_next;

        // ---- rebuild contiguous active list (ascending), 128-slot pad ----
        unsigned long long m = __ballot(zn > 0.0f);
        if (lane == 0) s_cnt[w] = __popcll(m);
        __syncthreads();   // [A] all reads of old list done; counts visible

        int base = 0, total = 0;
#pragma unroll
        for (int i = 0; i < 8; ++i) {
            int c = s_cnt[i];
            total += c;
            if (i < w) base += c;
        }
        if (zn > 0.0f) {
            int pos = base + __popcll(m & ((1ull << lane) - 1ull));
            s_list[pos] = u;
        }
        if (u == 0) s_total = total;
        if (u < WIN) s_list[total + u] = UNITS;      // pad idx -> zero row
        __syncthreads();   // [C] list ready
    }
}

extern "C" void kernel_launch(void* const* d_in, const int* in_sizes, int n_in,
                              void* d_out, int out_size, void* d_ws, size_t ws_size,
                              hipStream_t stream) {
    (void)in_sizes; (void)n_in; (void)out_size; (void)ws_size;
    const float* x     = (const float*)d_in[0];   // [B,T,128]
    const float* W_in  = (const float*)d_in[1];   // [128,512]
    const float* W_rec = (const float*)d_in[2];   // [512,512]
    float* out = (float*)d_out;                   // [B,T,512]
    float* Wz  = (float*)d_ws;                    // [513][512] zero-diag copy

    wz_prep<<<dim3(UNITS + 1), dim3(UNITS), 0, stream>>>(W_rec, Wz);
    gemm_in<<<dim3((B_SZ * T_SZ / 128) * (UNITS / 128)), dim3(256), 0, stream>>>(
        x, W_in, out);
    alif_scan<<<dim3(B_SZ), dim3(512), 0, stream>>>(Wz, out);
}

// Round 6
// 2205.874 us; speedup vs baseline: 1.4905x; 1.4905x over previous
//
#include <hip/hip_runtime.h>

#define B_SZ   256
#define T_SZ   1000
#define N_IN   128
#define UNITS  512

// ---------------------------------------------------------------------------
// Phase 0: Wz[513][512] in d_ws: W_rec with diagonal zeroed plus an all-zero
// row 512. Pad list slots (idx 512) and diagonal gathers return exact +0.0f,
// so the accumulation chain is unconditional yet bit-identical to the
// predicated r1 chain (proven absmax 0.0 in r5).
// ---------------------------------------------------------------------------
__global__ __launch_bounds__(512) void wz_prep(const float* __restrict__ Wr,
                                               float* __restrict__ Wz) {
    const int c = threadIdx.x, r = blockIdx.x;
    Wz[(size_t)r * UNITS + c] =
        (r >= UNITS || r == c) ? 0.0f : Wr[(size_t)r * UNITS + c];
}

// ---------------------------------------------------------------------------
// Phase 1: C[M,512] = X[M,128] @ W[128,512],  M = B*T = 256000, fp32.
// (unchanged — measured at ~fp32 vector roofline, ~210 us)
// ---------------------------------------------------------------------------
__global__ __launch_bounds__(256) void gemm_in(const float* __restrict__ X,
                                               const float* __restrict__ W,
                                               float* __restrict__ C) {
    __shared__ __align__(16) float As[32][128];  // As[k][m] (transposed x tile)
    __shared__ __align__(16) float Bs[32][128];  // Bs[k][n]

    const int tid = threadIdx.x;
    const int ntile = blockIdx.x & 3;        // 512/128 = 4 n-tiles
    const int mtile = blockIdx.x >> 2;       // 2000 m-tiles
    const int m0 = mtile * 128, n0 = ntile * 128;
    const int tm  = (tid >> 4) * 8;          // 16 m-groups of 8
    const int tn4 = (tid & 15) * 4;          // 16 n-groups of 4 (+ mirror at +64)

    float acc[8][8];
#pragma unroll
    for (int i = 0; i < 8; ++i)
#pragma unroll
        for (int j = 0; j < 8; ++j) acc[i][j] = 0.0f;

    for (int k0 = 0; k0 < 128; k0 += 32) {
        __syncthreads();
#pragma unroll
        for (int r = 0; r < 4; ++r) {
            int li  = r * 256 + tid;          // 0..1023 float4 slots
            int row = li >> 3;                // 0..127
            int ch  = li & 7;                 // 0..7 (4 floats each)
            float4 a = *(const float4*)&X[(size_t)(m0 + row) * 128 + k0 + ch * 4];
            As[ch * 4 + 0][row] = a.x;
            As[ch * 4 + 1][row] = a.y;
            As[ch * 4 + 2][row] = a.z;
            As[ch * 4 + 3][row] = a.w;
        }
#pragma unroll
        for (int r = 0; r < 4; ++r) {
            int li = r * 256 + tid;
            int kk = li >> 5;                 // 0..31
            int n4 = li & 31;                 // 0..31
            *(float4*)&Bs[kk][n4 * 4] =
                *(const float4*)&W[(size_t)(k0 + kk) * 512 + n0 + n4 * 4];
        }
        __syncthreads();

#pragma unroll 8
        for (int k = 0; k < 32; ++k) {
            float4 a0 = *(const float4*)&As[k][tm];
            float4 a1 = *(const float4*)&As[k][tm + 4];
            float4 b0 = *(const float4*)&Bs[k][tn4];
            float4 b1 = *(const float4*)&Bs[k][tn4 + 64];
            const float av[8] = {a0.x, a0.y, a0.z, a0.w, a1.x, a1.y, a1.z, a1.w};
            const float bv[8] = {b0.x, b0.y, b0.z, b0.w, b1.x, b1.y, b1.z, b1.w};
#pragma unroll
            for (int i = 0; i < 8; ++i)
#pragma unroll
                for (int j = 0; j < 8; ++j)
                    acc[i][j] = fmaf(av[i], bv[j], acc[i][j]);
        }
    }

#pragma unroll
    for (int i = 0; i < 8; ++i) {
        size_t row = (size_t)(m0 + tm + i) * 512;
        float4 c0 = make_float4(acc[i][0], acc[i][1], acc[i][2], acc[i][3]);
        float4 c1 = make_float4(acc[i][4], acc[i][5], acc[i][6], acc[i][7]);
        *(float4*)&C[row + n0 + tn4]      = c0;
        *(float4*)&C[row + n0 + 64 + tn4] = c1;
    }
}

// ---------------------------------------------------------------------------
// Phase 2: ALIF scan. TWO batches per 1024-thread block (grid = 128):
// threads [0,512) run batch 2*blockIdx, threads [512,1024) run batch
// 2*blockIdx+1 — each half is EXACTLY the proven r1 algorithm (contiguous
// ascending list, cross-wave prefix, 8-in-flight gather groups), upgraded
// with the r5-proven Wz trick (unconditional __fadd_rn chain; pad idx 512
// and diagonal fetch exact +0.0f). Rationale: scan is ~86% of the L2-BW
// floor with only 2 waves/SIMD; doubling resident waves (4/SIMD) hides the
// L2 gather latency while total L2 traffic (the XCD-shared resource) is
// unchanged. Barriers are block-wide; both halves execute identical barrier
// counts per step.
// ---------------------------------------------------------------------------
__global__ __launch_bounds__(1024, 1) void alif_scan(const float* __restrict__ Wz,
                                                     float* __restrict__ IO) {
    const int tid  = threadIdx.x;
    const int half = tid >> 9;               // 0/1: which batch of the pair
    const int u    = tid & 511;              // unit id within the batch
    const int w    = u >> 6;                 // wave-in-half (0..7)
    const int lane = tid & 63;
    const int b    = blockIdx.x * 2 + half;

    __shared__ __align__(16) int s_list[2][520];   // 512 + 8 pad each
    __shared__ int s_cnt[2][8];
    __shared__ int s_total[2];

    const float DECAY   = 0.95122942450071400910f;   // exp(-1/20)
    const float OMD     = 1.0f - DECAY;
    const float DECAY_B = 0.99501247919268232342f;   // exp(-1/200)
    const float OMDB    = 1.0f - DECAY_B;

    float v = 0.0f, ad = 0.0f, z = 0.0f;

    const float* wz = Wz + u;                         // column u of Wz
    float* io = IO + (size_t)b * (T_SZ * UNITS) + u;  // [t][u] slab for batch b
    int* lst = s_list[half];

    // init: pads + zero totals
    lst[u] = UNITS;
    if (u < 8) lst[UNITS + u] = UNITS;
    if (u == 0) s_total[half] = 0;
    __syncthreads();

    float i_cur = io[0];

    for (int t = 0; t < T_SZ; ++t) {
        // prefetch next step's input current
        float i_next = io[(t + 1 < T_SZ ? t + 1 : t) * UNITS];

        const int cnt = s_total[half];
        float acc = 0.0f;

        // ---- r1's proven 8-in-flight gather loop, unconditional adds ----
        for (int k = 0; k < cnt; k += 8) {
            int4 Ja = *(const int4*)(lst + k);
            int4 Jb = *(const int4*)(lst + k + 4);
            float g0 = wz[Ja.x * UNITS];
            float g1 = wz[Ja.y * UNITS];
            float g2 = wz[Ja.z * UNITS];
            float g3 = wz[Ja.w * UNITS];
            float g4 = wz[Jb.x * UNITS];
            float g5 = wz[Jb.y * UNITS];
            float g6 = wz[Jb.z * UNITS];
            float g7 = wz[Jb.w * UNITS];
            acc = __fadd_rn(acc, g0);
            acc = __fadd_rn(acc, g1);
            acc = __fadd_rn(acc, g2);
            acc = __fadd_rn(acc, g3);
            acc = __fadd_rn(acc, g4);
            acc = __fadd_rn(acc, g5);
            acc = __fadd_rn(acc, g6);
            acc = __fadd_rn(acc, g7);
        }

        // ---- elementwise state update — exact reference op order ----
        float newb = __fadd_rn(__fmul_rn(DECAY_B, ad), __fmul_rn(OMDB, z));
        float thr  = __fadd_rn(0.01f, __fmul_rn(newb, 1.6f));
        float it   = __fadd_rn(__fadd_rn(i_cur, acc), 0.0f);       // + ADD_CUR
        float ires = __fmul_rn(__fmul_rn(z, thr), 1.0f);           // * DT
        float newv = __fsub_rn(
            __fadd_rn(__fmul_rn(DECAY, v), __fmul_rn(OMD, it)), ires);
        float zn = (newv > thr) ? 1.0f : 0.0f;      // refractory is a no-op

        io[t * UNITS] = zn;                          // overwrite i_in with z
        v = newv; ad = newb; z = zn; i_cur = i_next;

        // ---- rebuild contiguous ascending active list (r1 scheme) ----
        unsigned long long m = __ballot(zn > 0.0f);  // wave is within one half
        if (lane == 0) s_cnt[half][w] = __popcll(m);
        __syncthreads();   // [A] all reads of old lists done; counts visible

        int base = 0, total = 0;
#pragma unroll
        for (int i = 0; i < 8; ++i) {
            int c = s_cnt[half][i];
            total += c;
            if (i < w) base += c;
        }
        if (zn > 0.0f) {
            int pos = base + __popcll(m & ((1ull << lane) - 1ull));
            lst[pos] = u;
        }
        if (u == 0) s_total[half] = total;
        if (u < 8) lst[total + u] = UNITS;           // pad idx -> zero row
        __syncthreads();   // [C] lists ready
    }
}

extern "C" void kernel_launch(void* const* d_in, const int* in_sizes, int n_in,
                              void* d_out, int out_size, void* d_ws, size_t ws_size,
                              hipStream_t stream) {
    (void)in_sizes; (void)n_in; (void)out_size; (void)ws_size;
    const float* x     = (const float*)d_in[0];   // [B,T,128]
    const float* W_in  = (const float*)d_in[1];   // [128,512]
    const float* W_rec = (const float*)d_in[2];   // [512,512]
    float* out = (float*)d_out;                   // [B,T,512]
    float* Wz  = (float*)d_ws;                    // [513][512] zero-diag copy

    wz_prep<<<dim3(UNITS + 1), dim3(UNITS), 0, stream>>>(W_rec, Wz);
    gemm_in<<<dim3((B_SZ * T_SZ / 128) * (UNITS / 128)), dim3(256), 0, stream>>>(
        x, W_in, out);
    // 2 batches per block -> 4 waves/SIMD for L2-latency hiding
    alif_scan<<<dim3(B_SZ / 2), dim3(1024), 0, stream>>>(Wz, out);
}